// Round 1
// baseline (104.547 us; speedup 1.0000x reference)
//
#include <hip/hip_runtime.h>
#include <math.h>

#define D 128

// Phase 0: fold W1,b1,W2,b2 into u[128], v[128], scalar c.
// out_e = tanh( u . f[src_e] + v . f[dst_e] + c )
__global__ void prep_kernel(const float* __restrict__ W1, const float* __restrict__ b1,
                            const float* __restrict__ W2, const float* __restrict__ b2,
                            float* __restrict__ uvc) {
    int d = threadIdx.x; // 0..127
    float u = 0.f, v = 0.f;
    for (int o = 0; o < D; ++o) {
        float wa = W2[o];
        float wb = W2[D + o];
        float w1 = W1[o * D + d];   // coalesced across threads
        u += (wa + wb) * w1;
        v += (wb - wa) * w1;
    }
    uvc[d] = u;
    uvc[D + d] = v;
    if (d == 0) {
        float c = b2[0];
        for (int o = 0; o < D; ++o) c += 2.f * W2[D + o] * b1[o];
        uvc[2 * D] = c;
    }
}

// Phase 1: per-node scalars s[n] = u.f[n], t[n] = v.f[n].
// One 64-lane wave per node; float2 per lane covers the 128-float row.
__global__ void node_kernel(const float* __restrict__ feat, const float* __restrict__ uvc,
                            float* __restrict__ s, float* __restrict__ t, int N) {
    int wave = (int)((blockIdx.x * blockDim.x + threadIdx.x) >> 6);
    int lane = threadIdx.x & 63;
    if (wave >= N) return;
    float2 fv = ((const float2*)(feat + (size_t)wave * D))[lane];
    float2 uu = ((const float2*)uvc)[lane];
    float2 vv = ((const float2*)(uvc + D))[lane];
    float su = fv.x * uu.x + fv.y * uu.y;
    float sv = fv.x * vv.x + fv.y * vv.y;
    #pragma unroll
    for (int off = 32; off; off >>= 1) {
        su += __shfl_xor(su, off, 64);
        sv += __shfl_xor(sv, off, 64);
    }
    if (lane == 0) { s[wave] = su; t[wave] = sv; }
}

// Phase 2: per-edge gather + tanh. 4 edges per thread, vectorized index loads.
__global__ void edge_kernel(const int* __restrict__ src, const int* __restrict__ dst,
                            const float* __restrict__ s, const float* __restrict__ t,
                            const float* __restrict__ uvc, float* __restrict__ out, int E) {
    int i = blockIdx.x * blockDim.x + threadIdx.x;
    int e0 = i * 4;
    if (e0 >= E) return;
    float c = uvc[2 * D];
    if (e0 + 3 < E) {
        int4 si = ((const int4*)src)[i];
        int4 di = ((const int4*)dst)[i];
        float4 r;
        r.x = tanhf(s[si.x] + t[di.x] + c);
        r.y = tanhf(s[si.y] + t[di.y] + c);
        r.z = tanhf(s[si.z] + t[di.z] + c);
        r.w = tanhf(s[si.w] + t[di.w] + c);
        ((float4*)out)[i] = r;
    } else {
        for (int e = e0; e < E; ++e)
            out[e] = tanhf(s[src[e]] + t[dst[e]] + c);
    }
}

// Fallback if workspace is too small for s/t: fused per-edge dot (wave per edge).
__global__ void fused_edge_kernel(const float* __restrict__ feat,
                                  const int* __restrict__ src, const int* __restrict__ dst,
                                  const float* __restrict__ uvc, float* __restrict__ out, int E) {
    int wave = (int)((blockIdx.x * blockDim.x + threadIdx.x) >> 6);
    int lane = threadIdx.x & 63;
    if (wave >= E) return;
    int sn = src[wave], dn = dst[wave];
    float2 fs = ((const float2*)(feat + (size_t)sn * D))[lane];
    float2 fd = ((const float2*)(feat + (size_t)dn * D))[lane];
    float2 uu = ((const float2*)uvc)[lane];
    float2 vv = ((const float2*)(uvc + D))[lane];
    float acc = fs.x * uu.x + fs.y * uu.y + fd.x * vv.x + fd.y * vv.y;
    #pragma unroll
    for (int off = 32; off; off >>= 1) acc += __shfl_xor(acc, off, 64);
    if (lane == 0) out[wave] = tanhf(acc + uvc[2 * D]);
}

extern "C" void kernel_launch(void* const* d_in, const int* in_sizes, int n_in,
                              void* d_out, int out_size, void* d_ws, size_t ws_size,
                              hipStream_t stream) {
    const float* feat = (const float*)d_in[0];
    const int*   src  = (const int*)d_in[1];
    const int*   dst  = (const int*)d_in[2];
    const float* W1   = (const float*)d_in[3];
    const float* b1   = (const float*)d_in[4];
    const float* W2   = (const float*)d_in[5];
    const float* b2   = (const float*)d_in[6];
    float* out = (float*)d_out;

    int N = in_sizes[0] / D;
    int E = in_sizes[1];

    float* uvc = (float*)d_ws;      // 257 floats used, pad to 512
    float* s   = uvc + 512;
    float* t   = s + N;
    size_t needed = (512 + 2 * (size_t)N) * sizeof(float);

    prep_kernel<<<1, D, 0, stream>>>(W1, b1, W2, b2, uvc);

    if (ws_size >= needed) {
        // node pass: one wave per node, 4 waves per 256-thread block
        int nblocks = (N + 3) / 4;
        node_kernel<<<nblocks, 256, 0, stream>>>(feat, uvc, s, t, N);
        // edge pass: 4 edges per thread
        int nthreads = (E + 3) / 4;
        edge_kernel<<<(nthreads + 255) / 256, 256, 0, stream>>>(src, dst, s, t, uvc, out, E);
    } else {
        int nblocks = (E + 3) / 4; // wave per edge
        fused_edge_kernel<<<nblocks, 256, 0, stream>>>(feat, src, dst, uvc, out, E);
    }
}

// Round 2
// 95.126 us; speedup vs baseline: 1.0990x; 1.0990x over previous
//
#include <hip/hip_runtime.h>
#include <math.h>

#define D 128

// out_e = tanh( u . f[src_e] + v . f[dst_e] + c )
//   u = W1^T (wa + wb),  v = W1^T (wb - wa),  c = 2*wb.b1 + b2
//   where wa = W2[0,:128], wb = W2[0,128:]

// Phase 0: fold weights. 512 threads: d = tid&127, o-chunk = tid>>7.
__global__ void prep_kernel(const float* __restrict__ W1, const float* __restrict__ b1,
                            const float* __restrict__ W2, const float* __restrict__ b2,
                            float* __restrict__ uvc) {
    __shared__ float su[4 * D];
    __shared__ float sv[4 * D];
    __shared__ float sc[D];
    int tid = threadIdx.x;          // 0..511
    int d = tid & (D - 1);
    int ch = tid >> 7;              // 0..3
    float u = 0.f, v = 0.f;
    int o0 = ch * 32;
    #pragma unroll 8
    for (int k = 0; k < 32; ++k) {
        int o = o0 + k;
        float wa = W2[o];
        float wb = W2[D + o];
        float w1 = W1[o * D + d];   // coalesced across d
        u += (wa + wb) * w1;
        v += (wb - wa) * w1;
    }
    su[ch * D + d] = u;
    sv[ch * D + d] = v;
    if (ch == 0) sc[d] = 2.f * W2[D + d] * b1[d];
    __syncthreads();
    if (tid < D) {
        float uu = su[d] + su[D + d] + su[2 * D + d] + su[3 * D + d];
        float vv = sv[d] + sv[D + d] + sv[2 * D + d] + sv[3 * D + d];
        uvc[2 * d]     = uu;        // interleaved u,v pairs
        uvc[2 * d + 1] = vv;
    } else if (tid == D) {
        float cc = b2[0];
        for (int o = 0; o < D; ++o) cc += sc[o];
        uvc[2 * D] = cc;
    }
}

// Phase 1: st[n] = (u.f[n], v.f[n]). Two nodes per wave, float4 per lane.
__global__ void node_kernel(const float* __restrict__ feat, const float* __restrict__ uvc,
                            float2* __restrict__ st, int N) {
    int wave = (int)((blockIdx.x * blockDim.x + threadIdx.x) >> 6);
    int lane = threadIdx.x & 63;
    int half = lane >> 5;           // 0 or 1
    int l = lane & 31;              // lane within half-wave
    int node = wave * 2 + half;
    if (node >= N) return;
    float4 f = ((const float4*)(feat + (size_t)node * D))[l];
    // uvc interleaved: pairs (u[d],v[d]); lane covers d = 4l..4l+3
    float4 a = ((const float4*)uvc)[2 * l];     // u[4l],v[4l],u[4l+1],v[4l+1]
    float4 b = ((const float4*)uvc)[2 * l + 1]; // u[4l+2],v[4l+2],u[4l+3],v[4l+3]
    float s = f.x * a.x + f.y * a.z + f.z * b.x + f.w * b.z;
    float t = f.x * a.y + f.y * a.w + f.z * b.y + f.w * b.w;
    #pragma unroll
    for (int off = 16; off; off >>= 1) {  // xor<32 stays within half-wave
        s += __shfl_xor(s, off, 64);
        t += __shfl_xor(t, off, 64);
    }
    if (l == 0) st[node] = make_float2(s, t);
}

// Phase 2: per-edge gather + tanh. 4 edges/thread; st gather = one 8B load/node.
__global__ void edge_kernel(const int* __restrict__ src, const int* __restrict__ dst,
                            const float2* __restrict__ st, const float* __restrict__ uvc,
                            float* __restrict__ out, int E) {
    int i = blockIdx.x * blockDim.x + threadIdx.x;
    int e0 = i * 4;
    if (e0 >= E) return;
    float c = uvc[2 * D];
    if (e0 + 3 < E) {
        int4 si = ((const int4*)src)[i];
        int4 di = ((const int4*)dst)[i];
        float2 a0 = st[si.x], a1 = st[si.y], a2 = st[si.z], a3 = st[si.w];
        float2 b0 = st[di.x], b1v = st[di.y], b2v = st[di.z], b3 = st[di.w];
        float4 r;
        r.x = tanhf(a0.x + b0.y + c);
        r.y = tanhf(a1.x + b1v.y + c);
        r.z = tanhf(a2.x + b2v.y + c);
        r.w = tanhf(a3.x + b3.y + c);
        ((float4*)out)[i] = r;
    } else {
        for (int e = e0; e < E; ++e)
            out[e] = tanhf(st[src[e]].x + st[dst[e]].y + c);
    }
}

// Fallback if workspace too small: fused per-edge dot (wave per edge).
__global__ void fused_edge_kernel(const float* __restrict__ feat,
                                  const int* __restrict__ src, const int* __restrict__ dst,
                                  const float* __restrict__ uvc, float* __restrict__ out, int E) {
    int wave = (int)((blockIdx.x * blockDim.x + threadIdx.x) >> 6);
    int lane = threadIdx.x & 63;
    if (wave >= E) return;
    int sn = src[wave], dn = dst[wave];
    float2 fs = ((const float2*)(feat + (size_t)sn * D))[lane];
    float2 fd = ((const float2*)(feat + (size_t)dn * D))[lane];
    float2 p = ((const float2*)uvc)[2 * lane];       // u,v for d=2*lane
    float2 q = ((const float2*)uvc)[2 * lane + 1];   // u,v for d=2*lane+1
    float acc = fs.x * p.x + fs.y * q.x + fd.x * p.y + fd.y * q.y;
    #pragma unroll
    for (int off = 32; off; off >>= 1) acc += __shfl_xor(acc, off, 64);
    if (lane == 0) out[wave] = tanhf(acc + uvc[2 * D]);
}

extern "C" void kernel_launch(void* const* d_in, const int* in_sizes, int n_in,
                              void* d_out, int out_size, void* d_ws, size_t ws_size,
                              hipStream_t stream) {
    const float* feat = (const float*)d_in[0];
    const int*   src  = (const int*)d_in[1];
    const int*   dst  = (const int*)d_in[2];
    const float* W1   = (const float*)d_in[3];
    const float* b1   = (const float*)d_in[4];
    const float* W2   = (const float*)d_in[5];
    const float* b2   = (const float*)d_in[6];
    float* out = (float*)d_out;

    int N = in_sizes[0] / D;
    int E = in_sizes[1];

    float* uvc = (float*)d_ws;              // 257 floats used, pad to 512
    float2* st = (float2*)((float*)d_ws + 512);
    size_t needed = (512 + 2 * (size_t)N) * sizeof(float);

    prep_kernel<<<1, 512, 0, stream>>>(W1, b1, W2, b2, uvc);

    if (ws_size >= needed) {
        // node pass: 2 nodes/wave, 4 waves per 256-thread block -> 8 nodes/block
        int nblocks = (N + 7) / 8;
        node_kernel<<<nblocks, 256, 0, stream>>>(feat, uvc, st, N);
        // edge pass: 4 edges per thread
        int nthreads = (E + 3) / 4;
        edge_kernel<<<(nthreads + 255) / 256, 256, 0, stream>>>(src, dst, st, uvc, out, E);
    } else {
        int nblocks = (E + 3) / 4;          // wave per edge
        fused_edge_kernel<<<nblocks, 256, 0, stream>>>(feat, src, dst, uvc, out, E);
    }
}